// Round 11
// baseline (64.416 us; speedup 1.0000x reference)
//
#include <hip/hip_runtime.h>
#include <hip/hip_fp16.h>
#include <math.h>

#define NROWS 50000
#define D 128
#define KNB 16

typedef _Float16 f16;
typedef _Float16 f16x8 __attribute__((ext_vector_type(8)));
typedef _Float16 f16x2 __attribute__((ext_vector_type(2)));
typedef float f32x4 __attribute__((ext_vector_type(4)));
typedef float f32x2 __attribute__((ext_vector_type(2)));
typedef unsigned int u32;

// ---- per-16-row pipeline: ssq -> fp8n row, A-frags -> [Yh|base] MFMA ----
__device__ __forceinline__ void process_rows(int row0, int r, int kg,
                                             const f32x4* __restrict__ v,
                                             const f16* __restrict__ wlds,
                                             const float* __restrict__ b,
                                             unsigned char* __restrict__ fp8n,
                                             f16* __restrict__ Yh,
                                             f16* __restrict__ baseh,
                                             float* __restrict__ basef,
                                             int use16) {
    float ssq = 0.f;
    #pragma unroll
    for (int q = 0; q < 8; ++q) {
        #pragma unroll
        for (int e = 0; e < 4; ++e) ssq = fmaf(v[q][e], v[q][e], ssq);
    }
    ssq += __shfl_xor(ssq, 16, 64);
    ssq += __shfl_xor(ssq, 32, 64);      // all lanes: full row ssq
    float rn = rsqrtf(ssq);

    // A-frags (f16, unnormalized) + fp8 e4m3 normalized row for the cosine table
    f16x8 a[4];
    #pragma unroll
    for (int kc = 0; kc < 4; ++kc) {
        f16x8 h;
        float nx[8];
        #pragma unroll
        for (int e = 0; e < 4; ++e) {
            float x0 = v[2 * kc][e], x1 = v[2 * kc + 1][e];
            h[e] = (f16)x0;        h[4 + e] = (f16)x1;
            nx[e] = x0 * rn;       nx[4 + e] = x1 * rn;
        }
        a[kc] = h;
        u32 lo = __builtin_amdgcn_cvt_pk_fp8_f32(nx[0], nx[1], 0u, false);
        lo     = __builtin_amdgcn_cvt_pk_fp8_f32(nx[2], nx[3], lo, true);
        u32 hi = __builtin_amdgcn_cvt_pk_fp8_f32(nx[4], nx[5], 0u, false);
        hi     = __builtin_amdgcn_cvt_pk_fp8_f32(nx[6], nx[7], hi, true);
        uint2 st; st.x = lo; st.y = hi;
        *(uint2*)(fp8n + (size_t)(row0 + r) * 128 + kc * 32 + kg * 8) = st;
    }

    #pragma unroll 4
    for (int ct = 0; ct < 16; ++ct) {
        int col = ct * 16 + r;
        f32x4 acc = {0.f, 0.f, 0.f, 0.f};
        #pragma unroll
        for (int kc = 0; kc < 4; ++kc) {
            int sc = (kc * 4 + kg) ^ r;  // swizzled chunk (matches staging XOR)
            f16x8 bf = *(const f16x8*)(wlds + col * 128 + sc * 8);
            acc = __builtin_amdgcn_mfma_f32_16x16x32_f16(a[kc], bf, acc, 0, 0, 0);
        }
        // C/D: col = lane&15 -> output channel; rows = row0 + kg*4 + i
        if (col < 128) {
            #pragma unroll
            for (int i = 0; i < 4; ++i)
                Yh[(size_t)(row0 + kg * 4 + i) * D + col] = (f16)acc[i];
        } else {
            float bias = b[col - 128];
            if (use16) {
                #pragma unroll
                for (int i = 0; i < 4; ++i)
                    baseh[(size_t)(row0 + kg * 4 + i) * D + (col - 128)] = (f16)(acc[i] + bias);
            } else {
                #pragma unroll
                for (int i = 0; i < 4; ++i)
                    basef[(size_t)(row0 + kg * 4 + i) * D + (col - 128)] = acc[i] + bias;
            }
        }
    }
}

// ---- fused gemm: W->LDS once per block; 256 rows/block (each wave: 2x16-row groups) ----
__global__ __launch_bounds__(512) void gemm_kernel(const float* __restrict__ fp,
                                                   const float* __restrict__ W,
                                                   const float* __restrict__ b,
                                                   unsigned char* __restrict__ fp8n,
                                                   f16* __restrict__ Yh,
                                                   f16* __restrict__ baseh,
                                                   float* __restrict__ basef,
                                                   int use16) {
    __shared__ f16 wlds[256 * 128];  // Wcat[col][k], chunk-swizzled: chunk ^= (col&15)
    int tid = threadIdx.x;
    int wid = tid >> 6, lane = tid & 63;
    int r = lane & 15, kg = lane >> 4;
    int rowA = blockIdx.x * 256 + wid * 16;          // first group
    int rowB = blockIdx.x * 256 + (wid + 8) * 16;    // second group
    bool validA = rowA < NROWS, validB = rowB < NROWS;

    // --- hoist first group's fp row loads above staging (latency overlap) ---
    f32x4 vA[8];
    if (validA) {
        const float* src = fp + (size_t)(rowA + r) * D + kg * 8;
        #pragma unroll
        for (int kc = 0; kc < 4; ++kc) {
            vA[2 * kc]     = *(const f32x4*)(src + kc * 32);
            vA[2 * kc + 1] = *(const f32x4*)(src + kc * 32 + 4);
        }
    }

    // stage W (128x256 f32) -> LDS as f16 concat layout, coalesced 32B reads per thread
    #pragma unroll
    for (int it = 0; it < 8; ++it) {
        int g = tid + it * 512;          // 8-float group, 4096 total
        int i = g * 8;                   // flat index into W
        int c_w = i >> 8;                // W row (0..127)
        int kk = i & 255;                // W col (0..255)
        int destrow = (kk < 128) ? c_w : c_w + 128;
        int k = kk & 127;
        int chunk = (k >> 3) ^ (destrow & 15);
        f32x4 v0 = *(const f32x4*)(W + i);
        f32x4 v1 = *(const f32x4*)(W + i + 4);
        f16x8 h;
        #pragma unroll
        for (int e = 0; e < 4; ++e) { h[e] = (f16)v0[e]; h[4 + e] = (f16)v1[e]; }
        *(f16x8*)(wlds + destrow * 128 + chunk * 8) = h;
    }
    __syncthreads();

    if (validA)
        process_rows(rowA, r, kg, vA, wlds, b, fp8n, Yh, baseh, basef, use16);

    if (validB) {
        f32x4 vB[8];
        const float* src = fp + (size_t)(rowB + r) * D + kg * 8;
        #pragma unroll
        for (int kc = 0; kc < 4; ++kc) {
            vB[2 * kc]     = *(const f32x4*)(src + kc * 32);
            vB[2 * kc + 1] = *(const f32x4*)(src + kc * 32 + 4);
        }
        process_rows(rowB, r, kg, vB, wlds, b, fp8n, Yh, baseh, basef, use16);
    }
}

// ---- main: one wave per n; all 16 Y-gathers issued first; fp8 cosine dots ----
__global__ __launch_bounds__(256) void main_kernel(const unsigned char* __restrict__ fp8n,
                                                   const int* __restrict__ idx,
                                                   const f16* __restrict__ Yh,
                                                   const f16* __restrict__ baseh,
                                                   float* __restrict__ out,
                                                   int use16) {
    int wid = threadIdx.x >> 6, lane = threadIdx.x & 63;
    int n = blockIdx.x * 4 + wid;
    int s = lane & 3, k = lane >> 2;

    int j = idx[(size_t)n * KNB + k];

    // issue the full Y gather set up front (memory-level parallelism)
    f16x2 yv[16];
    #pragma unroll
    for (int kk = 0; kk < KNB; ++kk) {
        int jk = __shfl(j, kk * 4, 64);
        yv[kk] = *(const f16x2*)(Yh + (size_t)jk * D + lane * 2);
    }
    float2 bv;
    if (use16) {
        f16x2 t = *(const f16x2*)(baseh + (size_t)n * D + lane * 2);
        bv.x = (float)t[0];
        bv.y = (float)t[1];
    } else {
        bv = *(const float2*)(out + (size_t)n * D + lane * 2);
    }

    // cosine dot on fp8-normalized rows: lane = (k, 32-elem slice s); w = dot directly
    const uint4* pj = (const uint4*)(fp8n + (size_t)j * 128 + s * 32);
    const uint4* pn = (const uint4*)(fp8n + (size_t)n * 128 + s * 32);
    uint4 xa = pj[0], xb = pj[1];
    uint4 ya = pn[0], yb = pn[1];
    float p = 0.f;
    auto dot4 = [&p](u32 xw, u32 yw) {
        f32x2 x0 = __builtin_amdgcn_cvt_pk_f32_fp8(xw, false);
        f32x2 x1 = __builtin_amdgcn_cvt_pk_f32_fp8(xw, true);
        f32x2 y0 = __builtin_amdgcn_cvt_pk_f32_fp8(yw, false);
        f32x2 y1 = __builtin_amdgcn_cvt_pk_f32_fp8(yw, true);
        p = fmaf(x0.x, y0.x, p); p = fmaf(x0.y, y0.y, p);
        p = fmaf(x1.x, y1.x, p); p = fmaf(x1.y, y1.y, p);
    };
    dot4(xa.x, ya.x); dot4(xa.y, ya.y); dot4(xa.z, ya.z); dot4(xa.w, ya.w);
    dot4(xb.x, yb.x); dot4(xb.y, yb.y); dot4(xb.z, yb.z); dot4(xb.w, yb.w);
    p += __shfl_xor(p, 1, 64);
    p += __shfl_xor(p, 2, 64);

    // combine: lane owns cols 2*lane, 2*lane+1
    float a0 = -INFINITY, a1 = -INFINITY;
    #pragma unroll
    for (int kk = 0; kk < KNB; ++kk) {
        float wk = __shfl(p, kk * 4, 64);
        a0 = fmaxf(a0, ((float)yv[kk][0] + bv.x) * wk);
        a1 = fmaxf(a1, ((float)yv[kk][1] + bv.y) * wk);
    }
    *(float2*)(out + (size_t)n * D + lane * 2) = make_float2(a0, a1);
}

extern "C" void kernel_launch(void* const* d_in, const int* in_sizes, int n_in,
                              void* d_out, int out_size, void* d_ws, size_t ws_size,
                              hipStream_t stream) {
    const float* fp  = (const float*)d_in[0];   // (N,128) f32
    const int*   idx = (const int*)d_in[1];     // (N,16) int32
    const float* W   = (const float*)d_in[2];   // (128,256) f32
    const float* b   = (const float*)d_in[3];   // (128,) f32
    float* out = (float*)d_out;                 // (N,128) f32

    char* ws = (char*)d_ws;
    unsigned char* fp8n = (unsigned char*)ws;            // 6.4 MB (fp8 e4m3 normalized rows)
    f16* Yh    = (f16*)(ws + (size_t)NROWS * 128);       // 12.8 MB
    f16* baseh = (f16*)(ws + (size_t)3 * NROWS * 128);   // 12.8 MB (only if ws large enough)

    // baseh path needs 32e6 bytes of workspace; otherwise keep base f32 in `out`
    int use16 = (ws_size >= (size_t)4 * NROWS * 128) ? 1 : 0;

    gemm_kernel<<<(NROWS + 255) / 256, 512, 0, stream>>>(fp, W, b, fp8n, Yh, baseh, out, use16);
    main_kernel<<<NROWS / 4, 256, 0, stream>>>(fp8n, idx, Yh, baseh, out, use16);
}